// Round 15
// baseline (180.707 us; speedup 1.0000x reference)
//
#include <hip/hip_runtime.h>
#include <cstddef>
#include <cstdint>

typedef __attribute__((ext_vector_type(8))) short short8;
typedef __attribute__((ext_vector_type(4))) short s16x4;
typedef __attribute__((ext_vector_type(4))) float f32x4;
typedef __attribute__((ext_vector_type(16))) float f32x16;

#define GLOAD_LDS16(gp, lp) __builtin_amdgcn_global_load_lds( \
    (const __attribute__((address_space(1))) void*)(gp),      \
    (__attribute__((address_space(3))) void*)(lp), 16, 0, 0)

__device__ __forceinline__ short f2bf(float f) {
    union { float f; unsigned u; } v; v.f = f;
    unsigned r = v.u + 0x7fffu + ((v.u >> 16) & 1u);
    return (short)(r >> 16);
}

// ---------------------------------------------------------------------------
// Prep: the 5 weight transposes only (f32 [R][C] -> bf16 [C][R]). 352 blocks.
// ---------------------------------------------------------------------------
__global__ __launch_bounds__(256) void prep_kernel(
    const float* __restrict__ Wq, const float* __restrict__ Wk,
    const float* __restrict__ Wv, const float* __restrict__ W1,
    const float* __restrict__ W2,
    short* WqT, short* WkT, short* WvT, short* W1T, short* W2T)
{
    __shared__ short tile[64][68];
    int b2 = blockIdx.x;
    const float* in; short* out; int R, C;
    if (b2 < 16)       { in = Wq; out = WqT; R = 512;  C = 128; }
    else if (b2 < 32)  { in = Wk; out = WkT; R = 512;  C = 128;  b2 -= 16; }
    else if (b2 < 96)  { in = Wv; out = WvT; R = 512;  C = 512;  b2 -= 32; }
    else if (b2 < 224) { in = W1; out = W1T; R = 512;  C = 1024; b2 -= 96; }
    else               { in = W2; out = W2T; R = 1024; C = 512;  b2 -= 224; }
    int nx = C >> 6;
    int r0 = (b2 / nx) * 64, c0 = (b2 % nx) * 64;
    int t = threadIdx.x, tr = t >> 6, tc = t & 63;
#pragma unroll
    for (int i = 0; i < 16; ++i) {
        int r = i * 4 + tr;
        tile[r][tc] = f2bf(in[(size_t)(r0 + r) * C + (c0 + tc)]);
    }
    __syncthreads();
#pragma unroll
    for (int i = 0; i < 16; ++i) {
        int r = i * 4 + tr;
        out[(size_t)(c0 + r) * R + (r0 + tc)] = tile[tc][r];
    }
}

// ---------------------------------------------------------------------------
// Fused q/k/v projection GEMM (f32 A, cvt while staging; B via
// global_load_lds). Outputs MFMA-fragment-major.
// ---------------------------------------------------------------------------
__global__ __launch_bounds__(256, 3) void proj_gemm(
    const float* __restrict__ x, const float* __restrict__ y,
    const short* __restrict__ WqT, const short* __restrict__ WkT,
    const short* __restrict__ WvT,
    short* __restrict__ qbf, short* __restrict__ kbff, short* __restrict__ vbf)
{
    __shared__ short As[128][64];
    __shared__ short Bs[128][64];
    int bid = blockIdx.x;
    const float* A; const short* BT; short* outp; int n0, N, mode, mb;
    if (bid < 128)      { A = x; BT = WqT; outp = qbf;  n0 = 0; N = 128; mode = 0; mb = bid; }
    else if (bid < 256) { A = y; BT = WkT; outp = kbff; n0 = 0; N = 128; mode = 0; mb = bid - 128; }
    else { int v2 = bid - 256; A = y; BT = WvT; outp = vbf; n0 = (v2 & 3) << 7; N = 512; mode = 1; mb = v2 >> 2; }
    const int m0 = mb << 7;
    const int K = 512;
    const int t = threadIdx.x, l = t & 63, w = t >> 6;
    const int wm = w >> 1, wn = w & 1;
    const int lo = l & 15, hi = l >> 4;

    f32x4 acc[4][4] = {};
    const int srow = l >> 3;
    const int scg  = (l & 7) ^ (srow & 7);

    for (int kt = 0; kt < K; kt += 64) {
#pragma unroll
        for (int i = 0; i < 4; ++i) {
            int seg = w * 4 + i;
            int row = seg * 8 + srow;
            GLOAD_LDS16(BT + (size_t)(n0 + row) * K + kt + scg * 8, &Bs[seg * 8][0]);
        }
#pragma unroll
        for (int i = 0; i < 4; ++i) {
            int c = i * 256 + t;
            int row = c >> 3, ch = c & 7;
            const float* src = A + (size_t)(m0 + row) * K + kt + ch * 8;
            f32x4 u0 = *(const f32x4*)src;
            f32x4 u1 = *(const f32x4*)(src + 4);
            int d0, d1, d2, d3;
            asm("v_cvt_pk_bf16_f32 %0, %1, %2" : "=v"(d0) : "v"(u0[0]), "v"(u0[1]));
            asm("v_cvt_pk_bf16_f32 %0, %1, %2" : "=v"(d1) : "v"(u0[2]), "v"(u0[3]));
            asm("v_cvt_pk_bf16_f32 %0, %1, %2" : "=v"(d2) : "v"(u1[0]), "v"(u1[1]));
            asm("v_cvt_pk_bf16_f32 %0, %1, %2" : "=v"(d3) : "v"(u1[2]), "v"(u1[3]));
            union { int i[4]; short8 v; } uu;
            uu.i[0] = d0; uu.i[1] = d1; uu.i[2] = d2; uu.i[3] = d3;
            *(short8*)&As[row][((ch ^ (row & 7)) * 8)] = uu.v;
        }
        __syncthreads();
#pragma unroll
        for (int kk = 0; kk < 2; ++kk) {
            short8 af[4], bfv[4];
            const int rc = ((kk * 4 + hi) ^ (lo & 7)) * 8;
#pragma unroll
            for (int mi = 0; mi < 4; ++mi)
                af[mi] = *(const short8*)&As[wm * 64 + mi * 16 + lo][rc];
#pragma unroll
            for (int ni = 0; ni < 4; ++ni)
                bfv[ni] = *(const short8*)&Bs[wn * 64 + ni * 16 + lo][rc];
            __builtin_amdgcn_s_setprio(1);
#pragma unroll
            for (int mi = 0; mi < 4; ++mi)
#pragma unroll
                for (int ni = 0; ni < 4; ++ni)
                    acc[mi][ni] = __builtin_amdgcn_mfma_f32_16x16x32_bf16(
                        af[mi], bfv[ni], acc[mi][ni], 0, 0, 0);
            __builtin_amdgcn_s_setprio(0);
        }
        __syncthreads();
    }

    if (mode == 0) {
#pragma unroll
        for (int mi = 0; mi < 4; ++mi) {
#pragma unroll
            for (int ni = 0; ni < 4; ++ni) {
                int rowb = m0 + wm * 64 + mi * 16 + hi * 4;
                int col  = n0 + wn * 64 + ni * 16 + lo;
                size_t base = ((size_t)(rowb >> 5) * (N >> 4) + (col >> 4)) * 512
                            + ((col & 15) >> 3) * 256 + (rowb & 31) * 8 + (col & 7);
#pragma unroll
                for (int r = 0; r < 4; ++r)
                    outp[base + r * 8] = f2bf(acc[mi][ni][r]);
            }
        }
    } else {
#pragma unroll
        for (int mi = 0; mi < 4; ++mi) {
#pragma unroll
            for (int ni = 0; ni < 4; ++ni) {
                int rowb = m0 + wm * 64 + mi * 16 + hi * 4;
                int col  = n0 + wn * 64 + ni * 16 + lo;
                size_t base = ((size_t)(rowb >> 4) * (N >> 5) + (col >> 5)) * 512
                            + ((rowb & 15) >> 3) * 256 + (col & 31) * 8 + (rowb & 7);
                s16x4 pk;
#pragma unroll
                for (int r = 0; r < 4; ++r) pk[r] = f2bf(acc[mi][ni][r]);
                *(s16x4*)(outp + base) = pk;
            }
        }
    }
}

// ---------------------------------------------------------------------------
// MLP GEMM with XCD-aware swizzle, 3 blocks/CU.
// EPI 2: +bias, exact GELU -> bf16. EPI 3: +bias +resid -> f32.
// ---------------------------------------------------------------------------
template<int EPI>
__global__ __launch_bounds__(256, 3) void gemm_kernel(
    const short* __restrict__ A, const short* __restrict__ BT, void* outv,
    const float* __restrict__ bias, const float* __restrict__ resid,
    int N, int K)
{
    __shared__ short As[128][64];
    __shared__ short Bs[128][64];
    int bid = blockIdx.x;
    const int cpx = gridDim.x >> 3;
    bid = (bid & 7) * cpx + (bid >> 3);     // XCD swizzle (grid % 8 == 0)
    const int nb = N >> 7;
    const int m0 = (bid / nb) << 7;
    const int n0 = (bid % nb) << 7;
    const int t = threadIdx.x, l = t & 63, w = t >> 6;
    const int wm = w >> 1, wn = w & 1;
    const int lo = l & 15, hi = l >> 4;

    f32x4 acc[4][4] = {};
    const int srow = l >> 3;
    const int scg  = (l & 7) ^ (srow & 7);

    for (int kt = 0; kt < K; kt += 64) {
#pragma unroll
        for (int i = 0; i < 4; ++i) {
            int seg = w * 4 + i;
            int row = seg * 8 + srow;
            GLOAD_LDS16(A + (size_t)(m0 + row) * K + kt + scg * 8, &As[seg * 8][0]);
        }
#pragma unroll
        for (int i = 0; i < 4; ++i) {
            int seg = w * 4 + i;
            int row = seg * 8 + srow;
            GLOAD_LDS16(BT + (size_t)(n0 + row) * K + kt + scg * 8, &Bs[seg * 8][0]);
        }
        __syncthreads();
#pragma unroll
        for (int kk = 0; kk < 2; ++kk) {
            short8 af[4], bfv[4];
            const int rc = ((kk * 4 + hi) ^ (lo & 7)) * 8;
#pragma unroll
            for (int mi = 0; mi < 4; ++mi)
                af[mi] = *(const short8*)&As[wm * 64 + mi * 16 + lo][rc];
#pragma unroll
            for (int ni = 0; ni < 4; ++ni)
                bfv[ni] = *(const short8*)&Bs[wn * 64 + ni * 16 + lo][rc];
            __builtin_amdgcn_s_setprio(1);
#pragma unroll
            for (int mi = 0; mi < 4; ++mi)
#pragma unroll
                for (int ni = 0; ni < 4; ++ni)
                    acc[mi][ni] = __builtin_amdgcn_mfma_f32_16x16x32_bf16(
                        af[mi], bfv[ni], acc[mi][ni], 0, 0, 0);
            __builtin_amdgcn_s_setprio(0);
        }
        __syncthreads();
    }

#pragma unroll
    for (int mi = 0; mi < 4; ++mi) {
#pragma unroll
        for (int ni = 0; ni < 4; ++ni) {
#pragma unroll
            for (int r = 0; r < 4; ++r) {
                int row = m0 + wm * 64 + mi * 16 + hi * 4 + r;
                int col = n0 + wn * 64 + ni * 16 + lo;
                size_t idx = (size_t)row * N + col;
                float v = acc[mi][ni][r];
                if (EPI == 2) {
                    v += bias[col];
                    v = 0.5f * v * (1.0f + erff(v * 0.70710678118654752f));
                    ((short*)outv)[idx] = f2bf(v);
                } else {
                    v += bias[col] + resid[idx];
                    ((float*)outv)[idx] = v;
                }
            }
        }
    }
}

// ---------------------------------------------------------------------------
// Flash attention + residual + FUSED LayerNorm. Fixed-m softmax.
// NEW: 16 waves (1024 thr) = 4 waves/SIMD for real TLP. KVBLK=256, 8 tiles.
// Wave (qh=w>>3, sub=w&7): QK on its 32q x 32k slice (no dup); PV on
// (qh, vd=sub*64..+64) -> o is only 32 VGPR. K/Q streamed per-MFMA, V in 4
// chunks of 4 kslots: peak live ~100 VGPR < hard 128 cap at 16 waves/CU.
// Ps[2][2][16][512] (64KB) parity double-buffer, 1 barrier/tile.
// ---------------------------------------------------------------------------
__global__ __launch_bounds__(1024, 1) void flash_kernel(
    const float* __restrict__ x,    // [8][2048][512] f32
    const short* __restrict__ qbf,  // frag-RC
    const short* __restrict__ kbff, // frag-RC
    const short* __restrict__ vbf,  // frag-CR
    float* __restrict__ xres,       // [8][2048][512] f32
    const float* __restrict__ gamma,
    const float* __restrict__ beta,
    short* __restrict__ hb)         // [16384][512] bf16 (LN output)
{
    __shared__ short Ps[2][2][16][512];  // [buf][qh][key16-blk][lane*8] 64 KB
    __shared__ float lpart[16][32];
    __shared__ float rsum[16][32];
    __shared__ float rsq[16][32];
    __shared__ float murs[2][64];

    const int bid = blockIdx.x;
    const int n = bid & 7;
    const int qtile = bid >> 3;          // 0..31 (64 q-rows)
    const int q0 = qtile << 6;
    const int t = threadIdx.x, l = t & 63, w = t >> 6;   // w = 0..15
    const int qh = w >> 3, sub = w & 7;
    const int lo5 = l & 31, hi2 = l >> 5;
    const float C1 = 0.08838834764831845f * 1.4426950408889634f; // scale*log2e

    const short* qp = qbf + (((size_t)(n * 64 + qtile * 2 + qh) * 8) << 9) + l * 8;
    const short* kb0 = kbff + (((size_t)(n * 64) * 8) << 9);

    f32x16 o0 = {}, o1 = {};             // 32q x {vd32, vd32+32}
    float lp = 0.f;
    short8 preg0, preg1;

    // ---- prologue: QK(0) on my slice + exp2 + pack -> Ps[0] ----
    {
        const short* kp = kb0 + (((size_t)(sub * 8)) << 9) + l * 8;
        f32x16 sa = {};
#pragma unroll
        for (int s = 0; s < 8; ++s) {
            short8 kf = *(const short8*)(kp + ((size_t)s << 9));
            short8 qv = *(const short8*)(qp + ((size_t)s << 9));
            sa = __builtin_amdgcn_mfma_f32_32x32x16_bf16(kf, qv, sa, 0, 0, 0);
        }
        float lsum = 0.f;
#pragma unroll
        for (int r = 0; r < 16; ++r) {
            float p = exp2f(sa[r] * C1);
            sa[r] = p; lsum += p;
        }
        lp = lsum;
        int wq[8], sx[8];
#pragma unroll
        for (int q2 = 0; q2 < 8; ++q2) {
            int a;
            asm("v_cvt_pk_bf16_f32 %0, %1, %2"
                : "=v"(a) : "v"(sa[2 * q2]), "v"(sa[2 * q2 + 1]));
            wq[q2] = a;
        }
#pragma unroll
        for (int q2 = 0; q2 < 8; ++q2) sx[q2] = __shfl_xor(wq[q2], 32);
        union { int i[4]; short8 v; } u0, u1;
        u0.i[0] = hi2 ? sx[2] : wq[0];
        u0.i[1] = hi2 ? sx[3] : wq[1];
        u0.i[2] = hi2 ? wq[2] : sx[0];
        u0.i[3] = hi2 ? wq[3] : sx[1];
        u1.i[0] = hi2 ? sx[6] : wq[4];
        u1.i[1] = hi2 ? sx[7] : wq[5];
        u1.i[2] = hi2 ? wq[6] : sx[4];
        u1.i[3] = hi2 ? wq[7] : sx[5];
        *(short8*)&Ps[0][qh][sub * 2][l * 8]     = u0.v;
        *(short8*)&Ps[0][qh][sub * 2 + 1][l * 8] = u1.v;
    }

    // ---- main loop: 8 tiles of 256 keys, 1 barrier each ----
    for (int kt2 = 0; kt2 < 8; ++kt2) {
        const bool hn = kt2 < 7;

        // QK(t+1) on my slice + fixed-m softmax + pack (reg-local)
        if (hn) {
            const short* kp = kb0 + (((size_t)(((kt2 + 1) * 8 + sub) * 8)) << 9) + l * 8;
            f32x16 sa = {};
            __builtin_amdgcn_s_setprio(1);
#pragma unroll
            for (int s = 0; s < 8; ++s) {
                short8 kf = *(const short8*)(kp + ((size_t)s << 9));
                short8 qv = *(const short8*)(qp + ((size_t)s << 9));
                sa = __builtin_amdgcn_mfma_f32_32x32x16_bf16(kf, qv, sa, 0, 0, 0);
            }
            __builtin_amdgcn_s_setprio(0);
            float lsum = 0.f;
#pragma unroll
            for (int r = 0; r < 16; ++r) {
                float p = exp2f(sa[r] * C1);
                sa[r] = p; lsum += p;
            }
            lp += lsum;
            int wq[8], sx[8];
#pragma unroll
            for (int q2 = 0; q2 < 8; ++q2) {
                int a;
                asm("v_cvt_pk_bf16_f32 %0, %1, %2"
                    : "=v"(a) : "v"(sa[2 * q2]), "v"(sa[2 * q2 + 1]));
                wq[q2] = a;
            }
#pragma unroll
            for (int q2 = 0; q2 < 8; ++q2) sx[q2] = __shfl_xor(wq[q2], 32);
            union { int i[4]; short8 v; } u0, u1;
            u0.i[0] = hi2 ? sx[2] : wq[0];
            u0.i[1] = hi2 ? sx[3] : wq[1];
            u0.i[2] = hi2 ? wq[2] : sx[0];
            u0.i[3] = hi2 ? wq[3] : sx[1];
            u1.i[0] = hi2 ? sx[6] : wq[4];
            u1.i[1] = hi2 ? sx[7] : wq[5];
            u1.i[2] = hi2 ? wq[6] : sx[4];
            u1.i[3] = hi2 ? wq[7] : sx[5];
            preg0 = u0.v; preg1 = u1.v;
        }

        __syncthreads();   // Ps[t&1] complete; publish (t+1)&1 is safe

        if (hn) {
            const int nb2 = (kt2 + 1) & 1;
            *(short8*)&Ps[nb2][qh][sub * 2][l * 8]     = preg0;
            *(short8*)&Ps[nb2][qh][sub * 2 + 1][l * 8] = preg1;
        }

        // PV(t): my (qh, vd-slice), 256 keys in 4 chunks of 4 kslots
        const int pb = kt2 & 1;
        const short* vp = vbf + ((((size_t)(n * 128 + kt2 * 16) * 16) + sub * 2) << 9) + l * 8;
#pragma unroll
        for (int ch = 0; ch < 4; ++ch) {
            short8 pa[4], vf[8];
#pragma unroll
            for (int j = 0; j < 4; ++j) {
                int ks = ch * 4 + j;
                pa[j]         = *(const short8*)&Ps[pb][qh][ks][l * 8];
                vf[j * 2]     = *(const short8*)(vp + (((size_t)(ks * 16)) << 9));
                vf[j * 2 + 1] = *(const short8*)(vp + (((size_t)(ks * 16 + 1)) << 9));
            }
            __builtin_amdgcn_s_setprio(1);
#pragma unroll
            for (int j = 0; j < 4; ++j) {
                o0 = __builtin_amdgcn_mfma_f32_32x32x16_bf16(pa[j], vf[j * 2],     o0, 0, 0, 0);
                o1 = __builtin_amdgcn_mfma_f32_32x32x16_bf16(pa[j], vf[j * 2 + 1], o1, 0, 0, 0);
            }
            __builtin_amdgcn_s_setprio(0);
        }
    }

    // ---- epilogue: l-merge, normalize, residual -> xres; fused LN -> hb ----
    float l2 = lp + __shfl_xor(lp, 32);
    if (l < 32) lpart[w][l] = l2;
    __syncthreads();
    float li;
    {
        const int b0 = qh * 8;
        li = 1.f / (lpart[b0][lo5] + lpart[b0 + 1][lo5] + lpart[b0 + 2][lo5] +
                    lpart[b0 + 3][lo5] + lpart[b0 + 4][lo5] + lpart[b0 + 5][lo5] +
                    lpart[b0 + 6][lo5] + lpart[b0 + 7][lo5]);
    }
    const int c0 = sub * 64 + lo5;
#pragma unroll
    for (int r = 0; r < 16; ++r) {
        int qr = (r & 3) + 8 * (r >> 2) + 4 * hi2;
        float ir = __shfl(li, qr);
        size_t base = ((size_t)(n * 2048 + q0 + qh * 32 + qr) << 9) + c0;
        float v0 = x[base]      + o0[r] * ir;
        float v1 = x[base + 32] + o1[r] * ir;
        xres[base] = v0; xres[base + 32] = v1;
        o0[r] = v0; o1[r] = v1;
        float s = v0 + v1;
        float sq = v0 * v0 + v1 * v1;
#pragma unroll
        for (int mm = 1; mm < 32; mm <<= 1) {
            s += __shfl_xor(s, mm); sq += __shfl_xor(sq, mm);
        }
        if (lo5 == 0) { rsum[w][qr] = s; rsq[w][qr] = sq; }
    }
    __syncthreads();
    if (t < 64) {
        const int bq = (t >> 5) * 8, qr = t & 31;
        float s = 0.f, qq = 0.f;
#pragma unroll
        for (int k = 0; k < 8; ++k) { s += rsum[bq + k][qr]; qq += rsq[bq + k][qr]; }
        float mu = s * (1.0f / 512.0f);
        float var = qq * (1.0f / 512.0f) - mu * mu;
        murs[0][t] = mu;
        murs[1][t] = rsqrtf(var + 1e-5f);
    }
    __syncthreads();
    const float g0 = gamma[c0], g1 = gamma[c0 + 32];
    const float e0 = beta[c0],  e1 = beta[c0 + 32];
#pragma unroll
    for (int r = 0; r < 16; ++r) {
        int qr = (r & 3) + 8 * (r >> 2) + 4 * hi2;
        float mu = murs[0][qh * 32 + qr], rs = murs[1][qh * 32 + qr];
        size_t base = ((size_t)(n * 2048 + q0 + qh * 32 + qr) << 9) + c0;
        hb[base]      = f2bf((o0[r] - mu) * rs * g0 + e0);
        hb[base + 32] = f2bf((o1[r] - mu) * rs * g1 + e1);
    }
}

// ---------------------------------------------------------------------------
extern "C" void kernel_launch(void* const* d_in, const int* in_sizes, int n_in,
                              void* d_out, int out_size, void* d_ws, size_t ws_size,
                              hipStream_t stream)
{
    const float* x     = (const float*)d_in[0];
    const float* y     = (const float*)d_in[1];
    const float* Wq    = (const float*)d_in[2];
    const float* Wk    = (const float*)d_in[3];
    const float* Wv    = (const float*)d_in[4];
    const float* gamma = (const float*)d_in[5];
    const float* beta  = (const float*)d_in[6];
    const float* W1    = (const float*)d_in[7];
    const float* b1    = (const float*)d_in[8];
    const float* W2    = (const float*)d_in[9];
    const float* b2    = (const float*)d_in[10];
    float* out = (float*)d_out;

    char* ws = (char*)d_ws;
    size_t off = 0;
    auto alloc = [&](size_t bytes) -> void* {
        void* p = ws + off;
        off += (bytes + 255) & ~(size_t)255;
        return p;
    };
    short* WqT  = (short*)alloc((size_t)128 * 512 * 2);
    short* WkT  = (short*)alloc((size_t)128 * 512 * 2);
    short* WvT  = (short*)alloc((size_t)512 * 512 * 2);
    short* W1T  = (short*)alloc((size_t)1024 * 512 * 2);
    short* W2T  = (short*)alloc((size_t)512 * 1024 * 2);
    short* qbf  = (short*)alloc((size_t)16384 * 128 * 2);   // frag-RC
    short* kbff = (short*)alloc((size_t)16384 * 128 * 2);   // frag-RC
    short* vbf  = (short*)alloc((size_t)16384 * 512 * 2);   // frag-CR
    short* hb   = (short*)alloc((size_t)16384 * 512 * 2);
    short* gb   = (short*)alloc((size_t)16384 * 1024 * 2);

    // 1. prep: weight transposes only
    prep_kernel<<<352, 256, 0, stream>>>(Wq, Wk, Wv, W1, W2,
                                         WqT, WkT, WvT, W1T, W2T);
    // 2. fused q/k/v projections (read f32 x,y directly) -> frag-major
    proj_gemm<<<768, 256, 0, stream>>>(x, y, WqT, WkT, WvT, qbf, kbff, vbf);
    // 3. attention + residual + fused LN -> xres(d_out), hb  [16 waves]
    flash_kernel<<<256, 1024, 0, stream>>>(x, qbf, kbff, vbf, out, gamma, beta, hb);
    // 4. MLP
    gemm_kernel<2><<<1024, 256, 0, stream>>>(hb, W1T, gb, b1, nullptr, 1024, 512);
    gemm_kernel<3><<<512,  256, 0, stream>>>(gb, W2T, out, b2, out, 512, 1024);

    (void)in_sizes; (void)n_in; (void)out_size; (void)ws_size;
}

// Round 16
// 170.263 us; speedup vs baseline: 1.0613x; 1.0613x over previous
//
#include <hip/hip_runtime.h>
#include <cstddef>
#include <cstdint>

typedef __attribute__((ext_vector_type(8))) short short8;
typedef __attribute__((ext_vector_type(4))) short s16x4;
typedef __attribute__((ext_vector_type(4))) float f32x4;
typedef __attribute__((ext_vector_type(16))) float f32x16;

#define GLOAD_LDS16(gp, lp) __builtin_amdgcn_global_load_lds( \
    (const __attribute__((address_space(1))) void*)(gp),      \
    (__attribute__((address_space(3))) void*)(lp), 16, 0, 0)

__device__ __forceinline__ short f2bf(float f) {
    union { float f; unsigned u; } v; v.f = f;
    unsigned r = v.u + 0x7fffu + ((v.u >> 16) & 1u);
    return (short)(r >> 16);
}

// ---------------------------------------------------------------------------
// Prep: the 5 weight transposes only (f32 [R][C] -> bf16 [C][R]). 352 blocks.
// ---------------------------------------------------------------------------
__global__ __launch_bounds__(256) void prep_kernel(
    const float* __restrict__ Wq, const float* __restrict__ Wk,
    const float* __restrict__ Wv, const float* __restrict__ W1,
    const float* __restrict__ W2,
    short* WqT, short* WkT, short* WvT, short* W1T, short* W2T)
{
    __shared__ short tile[64][68];
    int b2 = blockIdx.x;
    const float* in; short* out; int R, C;
    if (b2 < 16)       { in = Wq; out = WqT; R = 512;  C = 128; }
    else if (b2 < 32)  { in = Wk; out = WkT; R = 512;  C = 128;  b2 -= 16; }
    else if (b2 < 96)  { in = Wv; out = WvT; R = 512;  C = 512;  b2 -= 32; }
    else if (b2 < 224) { in = W1; out = W1T; R = 512;  C = 1024; b2 -= 96; }
    else               { in = W2; out = W2T; R = 1024; C = 512;  b2 -= 224; }
    int nx = C >> 6;
    int r0 = (b2 / nx) * 64, c0 = (b2 % nx) * 64;
    int t = threadIdx.x, tr = t >> 6, tc = t & 63;
#pragma unroll
    for (int i = 0; i < 16; ++i) {
        int r = i * 4 + tr;
        tile[r][tc] = f2bf(in[(size_t)(r0 + r) * C + (c0 + tc)]);
    }
    __syncthreads();
#pragma unroll
    for (int i = 0; i < 16; ++i) {
        int r = i * 4 + tr;
        out[(size_t)(c0 + r) * R + (r0 + tc)] = tile[tc][r];
    }
}

// ---------------------------------------------------------------------------
// Fused q/k/v projection GEMM (f32 A, cvt while staging; B via
// global_load_lds). Outputs MFMA-fragment-major.
// ---------------------------------------------------------------------------
__global__ __launch_bounds__(256, 3) void proj_gemm(
    const float* __restrict__ x, const float* __restrict__ y,
    const short* __restrict__ WqT, const short* __restrict__ WkT,
    const short* __restrict__ WvT,
    short* __restrict__ qbf, short* __restrict__ kbff, short* __restrict__ vbf)
{
    __shared__ short As[128][64];
    __shared__ short Bs[128][64];
    int bid = blockIdx.x;
    const float* A; const short* BT; short* outp; int n0, N, mode, mb;
    if (bid < 128)      { A = x; BT = WqT; outp = qbf;  n0 = 0; N = 128; mode = 0; mb = bid; }
    else if (bid < 256) { A = y; BT = WkT; outp = kbff; n0 = 0; N = 128; mode = 0; mb = bid - 128; }
    else { int v2 = bid - 256; A = y; BT = WvT; outp = vbf; n0 = (v2 & 3) << 7; N = 512; mode = 1; mb = v2 >> 2; }
    const int m0 = mb << 7;
    const int K = 512;
    const int t = threadIdx.x, l = t & 63, w = t >> 6;
    const int wm = w >> 1, wn = w & 1;
    const int lo = l & 15, hi = l >> 4;

    f32x4 acc[4][4] = {};
    const int srow = l >> 3;
    const int scg  = (l & 7) ^ (srow & 7);

    for (int kt = 0; kt < K; kt += 64) {
#pragma unroll
        for (int i = 0; i < 4; ++i) {
            int seg = w * 4 + i;
            int row = seg * 8 + srow;
            GLOAD_LDS16(BT + (size_t)(n0 + row) * K + kt + scg * 8, &Bs[seg * 8][0]);
        }
#pragma unroll
        for (int i = 0; i < 4; ++i) {
            int c = i * 256 + t;
            int row = c >> 3, ch = c & 7;
            const float* src = A + (size_t)(m0 + row) * K + kt + ch * 8;
            f32x4 u0 = *(const f32x4*)src;
            f32x4 u1 = *(const f32x4*)(src + 4);
            int d0, d1, d2, d3;
            asm("v_cvt_pk_bf16_f32 %0, %1, %2" : "=v"(d0) : "v"(u0[0]), "v"(u0[1]));
            asm("v_cvt_pk_bf16_f32 %0, %1, %2" : "=v"(d1) : "v"(u0[2]), "v"(u0[3]));
            asm("v_cvt_pk_bf16_f32 %0, %1, %2" : "=v"(d2) : "v"(u1[0]), "v"(u1[1]));
            asm("v_cvt_pk_bf16_f32 %0, %1, %2" : "=v"(d3) : "v"(u1[2]), "v"(u1[3]));
            union { int i[4]; short8 v; } uu;
            uu.i[0] = d0; uu.i[1] = d1; uu.i[2] = d2; uu.i[3] = d3;
            *(short8*)&As[row][((ch ^ (row & 7)) * 8)] = uu.v;
        }
        __syncthreads();
#pragma unroll
        for (int kk = 0; kk < 2; ++kk) {
            short8 af[4], bfv[4];
            const int rc = ((kk * 4 + hi) ^ (lo & 7)) * 8;
#pragma unroll
            for (int mi = 0; mi < 4; ++mi)
                af[mi] = *(const short8*)&As[wm * 64 + mi * 16 + lo][rc];
#pragma unroll
            for (int ni = 0; ni < 4; ++ni)
                bfv[ni] = *(const short8*)&Bs[wn * 64 + ni * 16 + lo][rc];
            __builtin_amdgcn_s_setprio(1);
#pragma unroll
            for (int mi = 0; mi < 4; ++mi)
#pragma unroll
                for (int ni = 0; ni < 4; ++ni)
                    acc[mi][ni] = __builtin_amdgcn_mfma_f32_16x16x32_bf16(
                        af[mi], bfv[ni], acc[mi][ni], 0, 0, 0);
            __builtin_amdgcn_s_setprio(0);
        }
        __syncthreads();
    }

    if (mode == 0) {
#pragma unroll
        for (int mi = 0; mi < 4; ++mi) {
#pragma unroll
            for (int ni = 0; ni < 4; ++ni) {
                int rowb = m0 + wm * 64 + mi * 16 + hi * 4;
                int col  = n0 + wn * 64 + ni * 16 + lo;
                size_t base = ((size_t)(rowb >> 5) * (N >> 4) + (col >> 4)) * 512
                            + ((col & 15) >> 3) * 256 + (rowb & 31) * 8 + (col & 7);
#pragma unroll
                for (int r = 0; r < 4; ++r)
                    outp[base + r * 8] = f2bf(acc[mi][ni][r]);
            }
        }
    } else {
#pragma unroll
        for (int mi = 0; mi < 4; ++mi) {
#pragma unroll
            for (int ni = 0; ni < 4; ++ni) {
                int rowb = m0 + wm * 64 + mi * 16 + hi * 4;
                int col  = n0 + wn * 64 + ni * 16 + lo;
                size_t base = ((size_t)(rowb >> 4) * (N >> 5) + (col >> 5)) * 512
                            + ((rowb & 15) >> 3) * 256 + (col & 31) * 8 + (rowb & 7);
                s16x4 pk;
#pragma unroll
                for (int r = 0; r < 4; ++r) pk[r] = f2bf(acc[mi][ni][r]);
                *(s16x4*)(outp + base) = pk;
            }
        }
    }
}

// ---------------------------------------------------------------------------
// MLP GEMM with XCD-aware swizzle, 3 blocks/CU.
// EPI 2: +bias, exact GELU -> bf16. EPI 3: +bias +resid -> f32.
// ---------------------------------------------------------------------------
template<int EPI>
__global__ __launch_bounds__(256, 3) void gemm_kernel(
    const short* __restrict__ A, const short* __restrict__ BT, void* outv,
    const float* __restrict__ bias, const float* __restrict__ resid,
    int N, int K)
{
    __shared__ short As[128][64];
    __shared__ short Bs[128][64];
    int bid = blockIdx.x;
    const int cpx = gridDim.x >> 3;
    bid = (bid & 7) * cpx + (bid >> 3);     // XCD swizzle (grid % 8 == 0)
    const int nb = N >> 7;
    const int m0 = (bid / nb) << 7;
    const int n0 = (bid % nb) << 7;
    const int t = threadIdx.x, l = t & 63, w = t >> 6;
    const int wm = w >> 1, wn = w & 1;
    const int lo = l & 15, hi = l >> 4;

    f32x4 acc[4][4] = {};
    const int srow = l >> 3;
    const int scg  = (l & 7) ^ (srow & 7);

    for (int kt = 0; kt < K; kt += 64) {
#pragma unroll
        for (int i = 0; i < 4; ++i) {
            int seg = w * 4 + i;
            int row = seg * 8 + srow;
            GLOAD_LDS16(A + (size_t)(m0 + row) * K + kt + scg * 8, &As[seg * 8][0]);
        }
#pragma unroll
        for (int i = 0; i < 4; ++i) {
            int seg = w * 4 + i;
            int row = seg * 8 + srow;
            GLOAD_LDS16(BT + (size_t)(n0 + row) * K + kt + scg * 8, &Bs[seg * 8][0]);
        }
        __syncthreads();
#pragma unroll
        for (int kk = 0; kk < 2; ++kk) {
            short8 af[4], bfv[4];
            const int rc = ((kk * 4 + hi) ^ (lo & 7)) * 8;
#pragma unroll
            for (int mi = 0; mi < 4; ++mi)
                af[mi] = *(const short8*)&As[wm * 64 + mi * 16 + lo][rc];
#pragma unroll
            for (int ni = 0; ni < 4; ++ni)
                bfv[ni] = *(const short8*)&Bs[wn * 64 + ni * 16 + lo][rc];
            __builtin_amdgcn_s_setprio(1);
#pragma unroll
            for (int mi = 0; mi < 4; ++mi)
#pragma unroll
                for (int ni = 0; ni < 4; ++ni)
                    acc[mi][ni] = __builtin_amdgcn_mfma_f32_16x16x32_bf16(
                        af[mi], bfv[ni], acc[mi][ni], 0, 0, 0);
            __builtin_amdgcn_s_setprio(0);
        }
        __syncthreads();
    }

#pragma unroll
    for (int mi = 0; mi < 4; ++mi) {
#pragma unroll
        for (int ni = 0; ni < 4; ++ni) {
#pragma unroll
            for (int r = 0; r < 4; ++r) {
                int row = m0 + wm * 64 + mi * 16 + hi * 4 + r;
                int col = n0 + wn * 64 + ni * 16 + lo;
                size_t idx = (size_t)row * N + col;
                float v = acc[mi][ni][r];
                if (EPI == 2) {
                    v += bias[col];
                    v = 0.5f * v * (1.0f + erff(v * 0.70710678118654752f));
                    ((short*)outv)[idx] = f2bf(v);
                } else {
                    v += bias[col] + resid[idx];
                    ((float*)outv)[idx] = v;
                }
            }
        }
    }
}

// ---------------------------------------------------------------------------
// Flash attention + residual + FUSED LayerNorm. Fixed-m softmax.
// FULL-ITERATION PREFETCH at (512,1)'s 256-VGPR cap (r8 schedule, which
// spilled at the 128 cap of (512,2), retried with headroom):
//   kf consumed by QK(t+1), then reloaded <- K(t+2);
//   vfa/vfb consumed by PV(t), then reloaded <- V(t+1).
// Peak live ~218 VGPR < 256. 1 barrier/tile; Ps parity double-buffer.
// ---------------------------------------------------------------------------
__global__ __launch_bounds__(512, 1) void flash_kernel(
    const float* __restrict__ x,    // [8][2048][512] f32
    const short* __restrict__ qbf,  // frag-RC
    const short* __restrict__ kbff, // frag-RC
    const short* __restrict__ vbf,  // frag-CR
    float* __restrict__ xres,       // [8][2048][512] f32
    const float* __restrict__ gamma,
    const float* __restrict__ beta,
    short* __restrict__ hb)         // [16384][512] bf16 (LN output)
{
    __shared__ short Ps[2][2][8][512];   // [buf][qh][key16-blk][lane*8] 32 KB
    __shared__ float lpart[8][32];
    __shared__ float rsum[8][64];
    __shared__ float rsq[8][64];
    __shared__ float murs[2][64];

    const int bid = blockIdx.x;
    const int n = bid & 7;
    const int qtile = bid >> 3;          // 0..31
    const int q0 = qtile << 6;
    const int t = threadIdx.x, l = t & 63, w = t >> 6;
    const int qh = w >> 2, kq = w & 3;
    const int lo5 = l & 31, hi2 = l >> 5;
    const float C1 = 0.08838834764831845f * 1.4426950408889634f; // scale*log2e

    // Q B-fragments for my q-half (32 q-rows)
    short8 qf[8];
    {
        const short* qp = qbf + (((size_t)(n * 64 + qtile * 2 + qh) * 8) << 9) + l * 8;
#pragma unroll
        for (int s = 0; s < 8; ++s) qf[s] = *(const short8*)(qp + (s << 9));
    }

    f32x16 o00 = {}, o01 = {}, o10 = {}, o11 = {};
    float lp = 0.f;

    const short* kb0 = kbff + (((size_t)(n * 64) * 8) << 9);
    const short* vb0 = vbf + ((((size_t)(n * 128)) * 16 + w * 2) << 9);

    short8 kf[8], vfa[8], vfb[8];
    short8 preg0, preg1;

    // ---- prologue: QK(0) + exp2 + pack -> Ps[0]; prefetch K(1), V(0) ----
    {
        const short* kp = kb0 + (((size_t)kq * 8) << 9) + l * 8;
#pragma unroll
        for (int s = 0; s < 8; ++s) kf[s] = *(const short8*)(kp + (s << 9));
        f32x16 sa = {};
        __builtin_amdgcn_s_setprio(1);
#pragma unroll
        for (int s = 0; s < 8; ++s)
            sa = __builtin_amdgcn_mfma_f32_32x32x16_bf16(kf[s], qf[s], sa, 0, 0, 0);
        __builtin_amdgcn_s_setprio(0);

        // prefetch K(1) and both V(0) halves (consumed next window)
        {
            const short* kp1 = kb0 + (((size_t)(4 + kq) * 8) << 9) + l * 8;
#pragma unroll
            for (int s = 0; s < 8; ++s) kf[s] = *(const short8*)(kp1 + (s << 9));
            const short* vp = vb0 + l * 8;
#pragma unroll
            for (int p = 0; p < 8; ++p)
                vfa[p] = *(const short8*)(vp + (((size_t)((p >> 1) * 16 + (p & 1))) << 9));
#pragma unroll
            for (int p = 0; p < 8; ++p)
                vfb[p] = *(const short8*)(vp + (((size_t)((4 + (p >> 1)) * 16 + (p & 1))) << 9));
        }

        float lsum = 0.f;
#pragma unroll
        for (int r = 0; r < 16; ++r) {
            float p = exp2f(sa[r] * C1);
            sa[r] = p; lsum += p;
        }
        lp = lsum;
        int wq[8], sx[8];
#pragma unroll
        for (int q2 = 0; q2 < 8; ++q2) {
            int a;
            asm("v_cvt_pk_bf16_f32 %0, %1, %2"
                : "=v"(a) : "v"(sa[2 * q2]), "v"(sa[2 * q2 + 1]));
            wq[q2] = a;
        }
#pragma unroll
        for (int q2 = 0; q2 < 8; ++q2) sx[q2] = __shfl_xor(wq[q2], 32);
        union { int i[4]; short8 v; } u0, u1;
        u0.i[0] = hi2 ? sx[2] : wq[0];
        u0.i[1] = hi2 ? sx[3] : wq[1];
        u0.i[2] = hi2 ? wq[2] : sx[0];
        u0.i[3] = hi2 ? wq[3] : sx[1];
        u1.i[0] = hi2 ? sx[6] : wq[4];
        u1.i[1] = hi2 ? sx[7] : wq[5];
        u1.i[2] = hi2 ? wq[6] : sx[4];
        u1.i[3] = hi2 ? wq[7] : sx[5];
        *(short8*)&Ps[0][qh][kq * 2][l * 8]     = u0.v;
        *(short8*)&Ps[0][qh][kq * 2 + 1][l * 8] = u1.v;
    }

    // ---- main loop: 16 tiles of 128 keys, 1 barrier each ----
    for (int kt2 = 0; kt2 < 16; ++kt2) {
        const bool hn = kt2 < 15;

        // QK(t+1) from prefetched kf + fixed-m softmax + pack -> preg
        if (hn) {
            f32x16 sa = {};
            __builtin_amdgcn_s_setprio(1);
#pragma unroll
            for (int s = 0; s < 8; ++s)
                sa = __builtin_amdgcn_mfma_f32_32x32x16_bf16(kf[s], qf[s], sa, 0, 0, 0);
            __builtin_amdgcn_s_setprio(0);
            // reload kf <- K(t+2)  (WAR: QK above consumed it)
            if (kt2 + 2 < 16) {
                const short* kp = kb0 + (((size_t)((kt2 + 2) * 4 + kq) * 8) << 9) + l * 8;
#pragma unroll
                for (int s = 0; s < 8; ++s) kf[s] = *(const short8*)(kp + (s << 9));
            }
            float lsum = 0.f;
#pragma unroll
            for (int r = 0; r < 16; ++r) {
                float p = exp2f(sa[r] * C1);
                sa[r] = p; lsum += p;
            }
            lp += lsum;
            int wq[8], sx[8];
#pragma unroll
            for (int q2 = 0; q2 < 8; ++q2) {
                int a;
                asm("v_cvt_pk_bf16_f32 %0, %1, %2"
                    : "=v"(a) : "v"(sa[2 * q2]), "v"(sa[2 * q2 + 1]));
                wq[q2] = a;
            }
#pragma unroll
            for (int q2 = 0; q2 < 8; ++q2) sx[q2] = __shfl_xor(wq[q2], 32);
            union { int i[4]; short8 v; } u0, u1;
            u0.i[0] = hi2 ? sx[2] : wq[0];
            u0.i[1] = hi2 ? sx[3] : wq[1];
            u0.i[2] = hi2 ? wq[2] : sx[0];
            u0.i[3] = hi2 ? wq[3] : sx[1];
            u1.i[0] = hi2 ? sx[6] : wq[4];
            u1.i[1] = hi2 ? sx[7] : wq[5];
            u1.i[2] = hi2 ? wq[6] : sx[4];
            u1.i[3] = hi2 ? wq[7] : sx[5];
            preg0 = u0.v; preg1 = u1.v;
        }

        __syncthreads();   // window boundary: Ps[t&1] writes visible

        // publish P(t+1) into the other parity buffer
        if (hn) {
            const int nb2 = (kt2 + 1) & 1;
            *(short8*)&Ps[nb2][qh][kq * 2][l * 8]     = preg0;
            *(short8*)&Ps[nb2][qh][kq * 2 + 1][l * 8] = preg1;
        }

        // PV(t): Ps[t&1] x V(t)  (vfa/vfb prefetched a full window ago)
        const int pb = kt2 & 1;
        __builtin_amdgcn_s_setprio(1);
#pragma unroll
        for (int ks = 0; ks < 4; ++ks) {
            short8 p0 = *(const short8*)&Ps[pb][0][ks][l * 8];
            short8 p1 = *(const short8*)&Ps[pb][1][ks][l * 8];
            o00 = __builtin_amdgcn_mfma_f32_32x32x16_bf16(p0, vfa[ks * 2 + 0], o00, 0, 0, 0);
            o01 = __builtin_amdgcn_mfma_f32_32x32x16_bf16(p0, vfa[ks * 2 + 1], o01, 0, 0, 0);
            o10 = __builtin_amdgcn_mfma_f32_32x32x16_bf16(p1, vfa[ks * 2 + 0], o10, 0, 0, 0);
            o11 = __builtin_amdgcn_mfma_f32_32x32x16_bf16(p1, vfa[ks * 2 + 1], o11, 0, 0, 0);
        }
#pragma unroll
        for (int ks = 4; ks < 8; ++ks) {
            short8 p0 = *(const short8*)&Ps[pb][0][ks][l * 8];
            short8 p1 = *(const short8*)&Ps[pb][1][ks][l * 8];
            o00 = __builtin_amdgcn_mfma_f32_32x32x16_bf16(p0, vfb[(ks - 4) * 2 + 0], o00, 0, 0, 0);
            o01 = __builtin_amdgcn_mfma_f32_32x32x16_bf16(p0, vfb[(ks - 4) * 2 + 1], o01, 0, 0, 0);
            o10 = __builtin_amdgcn_mfma_f32_32x32x16_bf16(p1, vfb[(ks - 4) * 2 + 0], o10, 0, 0, 0);
            o11 = __builtin_amdgcn_mfma_f32_32x32x16_bf16(p1, vfb[(ks - 4) * 2 + 1], o11, 0, 0, 0);
        }
        __builtin_amdgcn_s_setprio(0);

        // reload vfa/vfb <- V(t+1)  (WAR: PV above consumed them)
        if (hn) {
            const short* vp = vb0 + (((size_t)((kt2 + 1) * 128)) << 9) + l * 8;
#pragma unroll
            for (int p = 0; p < 8; ++p)
                vfa[p] = *(const short8*)(vp + (((size_t)((p >> 1) * 16 + (p & 1))) << 9));
#pragma unroll
            for (int p = 0; p < 8; ++p)
                vfb[p] = *(const short8*)(vp + (((size_t)((4 + (p >> 1)) * 16 + (p & 1))) << 9));
        }
    }

    // ---- epilogue: l-merge, normalize, residual -> xres; fused LN -> hb ----
    float l2 = lp + __shfl_xor(lp, 32);
    if (l < 32) lpart[w][l] = l2;
    __syncthreads();
    float li0 = 1.f / (lpart[0][lo5] + lpart[1][lo5] + lpart[2][lo5] + lpart[3][lo5]);
    float li1 = 1.f / (lpart[4][lo5] + lpart[5][lo5] + lpart[6][lo5] + lpart[7][lo5]);
    const int c0 = w * 64 + lo5;
#pragma unroll
    for (int r = 0; r < 16; ++r) {
        int qr = (r & 3) + 8 * (r >> 2) + 4 * hi2;
        float ir0 = __shfl(li0, qr);
        float ir1 = __shfl(li1, qr);
        size_t b0 = ((size_t)(n * 2048 + q0 + qr) << 9) + c0;
        size_t b1 = ((size_t)(n * 2048 + q0 + 32 + qr) << 9) + c0;
        float v00 = x[b0]      + o00[r] * ir0;
        float v01 = x[b0 + 32] + o01[r] * ir0;
        float v10 = x[b1]      + o10[r] * ir1;
        float v11 = x[b1 + 32] + o11[r] * ir1;
        xres[b0] = v00; xres[b0 + 32] = v01;
        xres[b1] = v10; xres[b1 + 32] = v11;
        o00[r] = v00; o01[r] = v01; o10[r] = v10; o11[r] = v11;
        float s0 = v00 + v01, sq0 = v00 * v00 + v01 * v01;
        float s1 = v10 + v11, sq1 = v10 * v10 + v11 * v11;
#pragma unroll
        for (int mm = 1; mm < 32; mm <<= 1) {
            s0 += __shfl_xor(s0, mm); sq0 += __shfl_xor(sq0, mm);
            s1 += __shfl_xor(s1, mm); sq1 += __shfl_xor(sq1, mm);
        }
        if (lo5 == 0) {
            rsum[w][qr] = s0;      rsq[w][qr] = sq0;
            rsum[w][32 + qr] = s1; rsq[w][32 + qr] = sq1;
        }
    }
    __syncthreads();
    if (t < 64) {
        float s = 0.f, qq = 0.f;
#pragma unroll
        for (int ww = 0; ww < 8; ++ww) { s += rsum[ww][t]; qq += rsq[ww][t]; }
        float mu = s * (1.0f / 512.0f);
        float var = qq * (1.0f / 512.0f) - mu * mu;
        murs[0][t] = mu;
        murs[1][t] = rsqrtf(var + 1e-5f);
    }
    __syncthreads();
    const float g0 = gamma[c0], g1 = gamma[c0 + 32];
    const float e0 = beta[c0],  e1 = beta[c0 + 32];
#pragma unroll
    for (int r = 0; r < 16; ++r) {
        int qr = (r & 3) + 8 * (r >> 2) + 4 * hi2;
        float mu0 = murs[0][qr],      rs0 = murs[1][qr];
        float mu1 = murs[0][32 + qr], rs1 = murs[1][32 + qr];
        size_t h0 = ((size_t)(n * 2048 + q0 + qr) << 9) + c0;
        size_t h1 = ((size_t)(n * 2048 + q0 + 32 + qr) << 9) + c0;
        hb[h0]      = f2bf((o00[r] - mu0) * rs0 * g0 + e0);
        hb[h0 + 32] = f2bf((o01[r] - mu0) * rs0 * g1 + e1);
        hb[h1]      = f2bf((o10[r] - mu1) * rs1 * g0 + e0);
        hb[h1 + 32] = f2bf((o11[r] - mu1) * rs1 * g1 + e1);
    }
}

// ---------------------------------------------------------------------------
extern "C" void kernel_launch(void* const* d_in, const int* in_sizes, int n_in,
                              void* d_out, int out_size, void* d_ws, size_t ws_size,
                              hipStream_t stream)
{
    const float* x     = (const float*)d_in[0];
    const float* y     = (const float*)d_in[1];
    const float* Wq    = (const float*)d_in[2];
    const float* Wk    = (const float*)d_in[3];
    const float* Wv    = (const float*)d_in[4];
    const float* gamma = (const float*)d_in[5];
    const float* beta  = (const float*)d_in[6];
    const float* W1    = (const float*)d_in[7];
    const float* b1    = (const float*)d_in[8];
    const float* W2    = (const float*)d_in[9];
    const float* b2    = (const float*)d_in[10];
    float* out = (float*)d_out;

    char* ws = (char*)d_ws;
    size_t off = 0;
    auto alloc = [&](size_t bytes) -> void* {
        void* p = ws + off;
        off += (bytes + 255) & ~(size_t)255;
        return p;
    };
    short* WqT  = (short*)alloc((size_t)128 * 512 * 2);
    short* WkT  = (short*)alloc((size_t)128 * 512 * 2);
    short* WvT  = (short*)alloc((size_t)512 * 512 * 2);
    short* W1T  = (short*)alloc((size_t)1024 * 512 * 2);
    short* W2T  = (short*)alloc((size_t)512 * 1024 * 2);
    short* qbf  = (short*)alloc((size_t)16384 * 128 * 2);   // frag-RC
    short* kbff = (short*)alloc((size_t)16384 * 128 * 2);   // frag-RC
    short* vbf  = (short*)alloc((size_t)16384 * 512 * 2);   // frag-CR
    short* hb   = (short*)alloc((size_t)16384 * 512 * 2);
    short* gb   = (short*)alloc((size_t)16384 * 1024 * 2);

    // 1. prep: weight transposes only
    prep_kernel<<<352, 256, 0, stream>>>(Wq, Wk, Wv, W1, W2,
                                         WqT, WkT, WvT, W1T, W2T);
    // 2. fused q/k/v projections (read f32 x,y directly) -> frag-major
    proj_gemm<<<768, 256, 0, stream>>>(x, y, WqT, WkT, WvT, qbf, kbff, vbf);
    // 3. attention + residual + fused LN -> xres(d_out), hb
    flash_kernel<<<256, 512, 0, stream>>>(x, qbf, kbff, vbf, out, gamma, beta, hb);
    // 4. MLP
    gemm_kernel<2><<<1024, 256, 0, stream>>>(hb, W1T, gb, b1, nullptr, 1024, 512);
    gemm_kernel<3><<<512,  256, 0, stream>>>(gb, W2T, out, b2, out, 512, 1024);

    (void)in_sizes; (void)n_in; (void)out_size; (void)ws_size;
}